// Round 1
// baseline (357.288 us; speedup 1.0000x reference)
//
#include <hip/hip_runtime.h>
#include <hip/hip_bf16.h>

// Problem: B=4, S=256, H=768, P=54.
// out[b,i,j,p] = valid(b,i,j) ? relu(ha[b,i]+hb[b,j]+bp1) . Wp2[p] + bp2[p] : 0
// valid = cand[b,i] & cand[b,j] & (i!=j); cand = (relu(x W1s^T + b1s) . W2s[0] + b2s[0]) > 0.5
// cand rate is ~1% (0.5 is ~2.3 sigma of span dist) -> compute pairs sparsely.

#define M_ROWS 1024   // B*S
#define HDIM 768
#define PDIM 54

// ---- workspace layout (bytes) ----
#define SPAN_OFF     0           // 1024 f32
#define CANDCNT_OFF  4096        // int
#define PAIRCNT_OFF  4100        // int
#define CANDIDX_OFF  8192        // 1024 int  (slot -> global row b*256+s)
#define CANDSLOT_OFF 12288       // 1024 int  (global row -> slot or -1)
#define PAIR_OFF     16384       // up to 262144 int (packed b*65536+i*256+j)
#define HA_OFF       1064960     // 1024*768 f32 (per-slot ha)
#define HB_OFF       4210688     // 1024*768 f32 (per-slot hb)

// ---------------- GEMM: h = relu(x @ W1s^T + b1s); span += h . W2s[0] ----------------
// M=1024, N=768, K=768. BM=BN=64, BK=16, 256 threads, 4x4 microtile.
__global__ __launch_bounds__(256) void gemm_span_kernel(
    const float* __restrict__ x, const float* __restrict__ W1,
    const float* __restrict__ b1, const float* __restrict__ w2row,
    float* __restrict__ span)
{
    __shared__ float As[16][65];
    __shared__ float Bs[16][65];
    __shared__ float rowpart[64][17];

    const int m0 = blockIdx.x * 64;
    const int n0 = blockIdx.y * 64;
    const int t  = threadIdx.x;
    const int tm = t & 15;
    const int tn = t >> 4;

    float acc[4][4] = {};

    const int r  = t >> 2;        // 0..63
    const int c4 = (t & 3) * 4;   // 0,4,8,12

    for (int k0 = 0; k0 < HDIM; k0 += 16) {
        float4 av = *(const float4*)(x  + (size_t)(m0 + r) * HDIM + k0 + c4);
        float4 bv = *(const float4*)(W1 + (size_t)(n0 + r) * HDIM + k0 + c4);
        As[c4+0][r] = av.x; As[c4+1][r] = av.y; As[c4+2][r] = av.z; As[c4+3][r] = av.w;
        Bs[c4+0][r] = bv.x; Bs[c4+1][r] = bv.y; Bs[c4+2][r] = bv.z; Bs[c4+3][r] = bv.w;
        __syncthreads();
        #pragma unroll
        for (int kk = 0; kk < 16; ++kk) {
            float a[4], b[4];
            #pragma unroll
            for (int i = 0; i < 4; ++i) a[i] = As[kk][tm * 4 + i];
            #pragma unroll
            for (int j = 0; j < 4; ++j) b[j] = Bs[kk][tn * 4 + j];
            #pragma unroll
            for (int i = 0; i < 4; ++i)
                #pragma unroll
                for (int j = 0; j < 4; ++j)
                    acc[i][j] += a[i] * b[j];
        }
        __syncthreads();
    }

    // epilogue: relu(acc + b1[n]) * w2row[n], reduce over this block's n-range
    float part[4];
    #pragma unroll
    for (int i = 0; i < 4; ++i) {
        float s = 0.f;
        #pragma unroll
        for (int j = 0; j < 4; ++j) {
            int n = n0 + tn * 4 + j;
            float h = acc[i][j] + b1[n];
            h = h > 0.f ? h : 0.f;
            s += h * w2row[n];
        }
        part[i] = s;
    }
    #pragma unroll
    for (int i = 0; i < 4; ++i) rowpart[tm * 4 + i][tn] = part[i];
    __syncthreads();
    if (t < 64) {
        float s = 0.f;
        #pragma unroll
        for (int c = 0; c < 16; ++c) s += rowpart[t][c];
        atomicAdd(&span[m0 + t], s);
    }
}

// ---------------- cand compaction ----------------
__global__ void cand_kernel(const float* __restrict__ span, const float* __restrict__ b2,
                            int* __restrict__ candCount, int* __restrict__ candIdx,
                            int* __restrict__ candSlot)
{
    int i = blockIdx.x * 256 + threadIdx.x;  // 0..1023
    float v = span[i] + b2[0];
    if (v > 0.5f) {
        int s = atomicAdd(candCount, 1);
        candIdx[s] = i;
        candSlot[i] = s;
    } else {
        candSlot[i] = -1;
    }
}

// ---------------- ha/hb only at cand rows ----------------
// ha[slot][k] = x[row] . Wp1[k][0:768]; hb[slot][k] = x[row] . Wp1[k][768:1536]
__global__ __launch_bounds__(256) void hab_kernel(
    const float* __restrict__ x, const float* __restrict__ Wp1,
    const int* __restrict__ candCount, const int* __restrict__ candIdx,
    float* __restrict__ ha, float* __restrict__ hb)
{
    __shared__ float xs[HDIM];
    const int nc = *candCount;
    for (int slot = blockIdx.x; slot < nc; slot += gridDim.x) {
        int row = candIdx[slot];
        for (int h = threadIdx.x; h < HDIM; h += 256)
            xs[h] = x[(size_t)row * HDIM + h];
        __syncthreads();
        for (int k = threadIdx.x; k < HDIM; k += 256) {
            const float* wr = Wp1 + (size_t)k * (2 * HDIM);
            float sa = 0.f, sb = 0.f;
            for (int h = 0; h < HDIM; h += 4) {
                float4 xv = *(const float4*)(xs + h);
                float4 wa = *(const float4*)(wr + h);
                float4 wb = *(const float4*)(wr + HDIM + h);
                sa += xv.x * wa.x + xv.y * wa.y + xv.z * wa.z + xv.w * wa.w;
                sb += xv.x * wb.x + xv.y * wb.y + xv.z * wb.z + xv.w * wb.w;
            }
            ha[(size_t)slot * HDIM + k] = sa;
            hb[(size_t)slot * HDIM + k] = sb;
        }
        __syncthreads();
    }
}

// ---------------- build valid pair list ----------------
__global__ void pairs_kernel(const int* __restrict__ candSlot,
                             int* __restrict__ pairCount, int* __restrict__ pairList)
{
    int idx = blockIdx.x * 256 + threadIdx.x;  // b*65536 + i*256 + j, 0..262143
    int b = idx >> 16;
    int i = (idx >> 8) & 255;
    int j = idx & 255;
    if (i == j) return;
    if (candSlot[b * 256 + i] >= 0 && candSlot[b * 256 + j] >= 0) {
        int p = atomicAdd(pairCount, 1);
        pairList[p] = idx;
    }
}

// ---------------- sparse pair logits ----------------
__global__ __launch_bounds__(256) void pair_kernel(
    const float* __restrict__ ha, const float* __restrict__ hb,
    const float* __restrict__ bp1, const float* __restrict__ Wp2,
    const float* __restrict__ bp2, const int* __restrict__ candSlot,
    const int* __restrict__ pairCount, const int* __restrict__ pairList,
    float* __restrict__ out)
{
    __shared__ float v[HDIM];
    const int np = *pairCount;
    for (int p = blockIdx.x; p < np; p += gridDim.x) {
        int idx = pairList[p];
        int b = idx >> 16;
        int i = (idx >> 8) & 255;
        int j = idx & 255;
        int si = candSlot[b * 256 + i];
        int sj = candSlot[b * 256 + j];
        for (int h = threadIdx.x; h < HDIM; h += 256) {
            float t = ha[(size_t)si * HDIM + h] + hb[(size_t)sj * HDIM + h] + bp1[h];
            v[h] = t > 0.f ? t : 0.f;
        }
        __syncthreads();
        if (threadIdx.x < PDIM) {
            const float* w = Wp2 + (size_t)threadIdx.x * HDIM;
            float s = 0.f;
            for (int h = 0; h < HDIM; h += 4) {
                float4 vv = *(const float4*)(v + h);
                float4 wv = *(const float4*)(w + h);
                s += vv.x * wv.x + vv.y * wv.y + vv.z * wv.z + vv.w * wv.w;
            }
            out[(size_t)idx * PDIM + threadIdx.x] = s + bp2[threadIdx.x];
        }
        __syncthreads();
    }
}

extern "C" void kernel_launch(void* const* d_in, const int* in_sizes, int n_in,
                              void* d_out, int out_size, void* d_ws, size_t ws_size,
                              hipStream_t stream) {
    const float* x   = (const float*)d_in[0];  // 4*256*768
    const float* W1s = (const float*)d_in[1];  // 768*768
    const float* b1s = (const float*)d_in[2];  // 768
    const float* W2s = (const float*)d_in[3];  // 2*768 (row 0 used)
    const float* b2s = (const float*)d_in[4];  // 2
    const float* Wp1 = (const float*)d_in[5];  // 768*1536
    const float* bp1 = (const float*)d_in[6];  // 768
    const float* Wp2 = (const float*)d_in[7];  // 54*768
    const float* bp2 = (const float*)d_in[8];  // 54

    char* ws = (char*)d_ws;
    float* span     = (float*)(ws + SPAN_OFF);
    int*   candCnt  = (int*)(ws + CANDCNT_OFF);
    int*   pairCnt  = (int*)(ws + PAIRCNT_OFF);
    int*   candIdx  = (int*)(ws + CANDIDX_OFF);
    int*   candSlot = (int*)(ws + CANDSLOT_OFF);
    int*   pairList = (int*)(ws + PAIR_OFF);
    float* ha       = (float*)(ws + HA_OFF);
    float* hb       = (float*)(ws + HB_OFF);

    float* out = (float*)d_out;

    // zero output (masked regions must be exactly 0) and span/counters
    hipMemsetAsync(out, 0, (size_t)out_size * sizeof(float), stream);
    hipMemsetAsync(ws, 0, 8192, stream);  // span + counters

    dim3 gGemm(M_ROWS / 64, HDIM / 64);
    gemm_span_kernel<<<gGemm, 256, 0, stream>>>(x, W1s, b1s, W2s, span);

    cand_kernel<<<4, 256, 0, stream>>>(span, b2s, candCnt, candIdx, candSlot);

    hab_kernel<<<256, 256, 0, stream>>>(x, Wp1, candCnt, candIdx, ha, hb);

    pairs_kernel<<<1024, 256, 0, stream>>>(candSlot, pairCnt, pairList);

    pair_kernel<<<256, 256, 0, stream>>>(ha, hb, bp1, Wp2, bp2,
                                         candSlot, pairCnt, pairList, out);
}

// Round 2
// 187.790 us; speedup vs baseline: 1.9026x; 1.9026x over previous
//
#include <hip/hip_runtime.h>
#include <hip/hip_bf16.h>

// Problem: B=4, S=256, H=768, P=54.
// out[b,i,j,p] = valid(b,i,j) ? relu(ha[b,i]+hb[b,j]+bp1) . Wp2[p] + bp2[p] : 0
// valid = cand[b,i] & cand[b,j] & (i!=j); cand = (relu(x W1s^T + b1s) . W2s[0] + b2s[0]) > 0.5
// cand rate ~1% -> sparse pair computation.
// R1 lesson: one block reading all of Wp1 = per-CU BW bound (4.7MB / 24GB/s = 196us).
//            Split Wp1's k-dim across blocks (KCHUNK=16 -> nc*48 blocks, 98KB each).

#define M_ROWS 1024   // B*S
#define HDIM 768
#define PDIM 54
#define KCHUNK 16
#define NKC (HDIM / KCHUNK)   // 48

// ---- workspace layout (bytes) ----
#define SPAN_OFF     0           // 1024 f32
#define CANDCNT_OFF  4096        // int
#define PAIRCNT_OFF  4100        // int
#define CANDIDX_OFF  8192        // 1024 int  (slot -> global row b*256+s)
#define CANDSLOT_OFF 12288       // 1024 int  (global row -> slot or -1)
#define PAIR_OFF     16384       // up to 262144 int (packed b*65536+i*256+j)
#define HA_OFF       1064960     // 1024*768 f32 (per-slot ha)
#define HB_OFF       4210688     // 1024*768 f32 (per-slot hb)

// ---------------- GEMM: h = relu(x @ W1s^T + b1s); span += h . W2s[0] ----------------
// M=1024, N=768, K=768. BM=BN=64, BK=16, 256 threads, 4x4 microtile.
__global__ __launch_bounds__(256) void gemm_span_kernel(
    const float* __restrict__ x, const float* __restrict__ W1,
    const float* __restrict__ b1, const float* __restrict__ w2row,
    float* __restrict__ span)
{
    __shared__ float As[16][65];
    __shared__ float Bs[16][65];
    __shared__ float rowpart[64][17];

    const int m0 = blockIdx.x * 64;
    const int n0 = blockIdx.y * 64;
    const int t  = threadIdx.x;
    const int tm = t & 15;
    const int tn = t >> 4;

    float acc[4][4] = {};

    const int r  = t >> 2;        // 0..63
    const int c4 = (t & 3) * 4;   // 0,4,8,12

    for (int k0 = 0; k0 < HDIM; k0 += 16) {
        float4 av = *(const float4*)(x  + (size_t)(m0 + r) * HDIM + k0 + c4);
        float4 bv = *(const float4*)(W1 + (size_t)(n0 + r) * HDIM + k0 + c4);
        As[c4+0][r] = av.x; As[c4+1][r] = av.y; As[c4+2][r] = av.z; As[c4+3][r] = av.w;
        Bs[c4+0][r] = bv.x; Bs[c4+1][r] = bv.y; Bs[c4+2][r] = bv.z; Bs[c4+3][r] = bv.w;
        __syncthreads();
        #pragma unroll
        for (int kk = 0; kk < 16; ++kk) {
            float a[4], b[4];
            #pragma unroll
            for (int i = 0; i < 4; ++i) a[i] = As[kk][tm * 4 + i];
            #pragma unroll
            for (int j = 0; j < 4; ++j) b[j] = Bs[kk][tn * 4 + j];
            #pragma unroll
            for (int i = 0; i < 4; ++i)
                #pragma unroll
                for (int j = 0; j < 4; ++j)
                    acc[i][j] += a[i] * b[j];
        }
        __syncthreads();
    }

    // epilogue: relu(acc + b1[n]) * w2row[n], reduce over this block's n-range
    float part[4];
    #pragma unroll
    for (int i = 0; i < 4; ++i) {
        float s = 0.f;
        #pragma unroll
        for (int j = 0; j < 4; ++j) {
            int n = n0 + tn * 4 + j;
            float h = acc[i][j] + b1[n];
            h = h > 0.f ? h : 0.f;
            s += h * w2row[n];
        }
        part[i] = s;
    }
    #pragma unroll
    for (int i = 0; i < 4; ++i) rowpart[tm * 4 + i][tn] = part[i];
    __syncthreads();
    if (t < 64) {
        float s = 0.f;
        #pragma unroll
        for (int c = 0; c < 16; ++c) s += rowpart[t][c];
        atomicAdd(&span[m0 + t], s);
    }
}

// ---------------- cand compaction ----------------
__global__ void cand_kernel(const float* __restrict__ span, const float* __restrict__ b2,
                            int* __restrict__ candCount, int* __restrict__ candIdx,
                            int* __restrict__ candSlot)
{
    int i = blockIdx.x * 256 + threadIdx.x;  // 0..1023
    float v = span[i] + b2[0];
    if (v > 0.5f) {
        int s = atomicAdd(candCount, 1);
        candIdx[s] = i;
        candSlot[i] = s;
    } else {
        candSlot[i] = -1;
    }
}

// ---------------- ha/hb only at cand rows, k-split across blocks ----------------
// work item = (slot, kc): block computes ha/hb[slot][kc*16 .. kc*16+15].
// Per block: 16 k-rows of Wp1 (98KB), shared across slots via L2.
// Thread t: k = kc*16 + (t>>4), h covers (t&15)*4 + 64*iter (coalesced 256B runs).
__global__ __launch_bounds__(256) void hab_kernel(
    const float* __restrict__ x, const float* __restrict__ Wp1,
    const int* __restrict__ candCount, const int* __restrict__ candIdx,
    float* __restrict__ ha, float* __restrict__ hb)
{
    __shared__ float xs[HDIM];
    __shared__ float red[2][KCHUNK][17];
    const int nc = *candCount;
    const int nitems = nc * NKC;
    const int kk  = threadIdx.x >> 4;       // 0..15: k within chunk
    const int hb0 = (threadIdx.x & 15) * 4; // h start: 16 lanes -> 256B contiguous

    for (int item = blockIdx.x; item < nitems; item += gridDim.x) {
        int slot = item / NKC;
        int kc   = item % NKC;
        int row  = candIdx[slot];

        for (int h = threadIdx.x; h < HDIM; h += 256)
            xs[h] = x[(size_t)row * HDIM + h];
        __syncthreads();

        int k = kc * KCHUNK + kk;
        const float* wr = Wp1 + (size_t)k * (2 * HDIM);
        float sa = 0.f, sb = 0.f;
        #pragma unroll
        for (int h = hb0; h < HDIM; h += 64) {
            float4 xv = *(const float4*)(xs + h);
            float4 wa = *(const float4*)(wr + h);
            float4 wb = *(const float4*)(wr + HDIM + h);
            sa += xv.x * wa.x + xv.y * wa.y + xv.z * wa.z + xv.w * wa.w;
            sb += xv.x * wb.x + xv.y * wb.y + xv.z * wb.z + xv.w * wb.w;
        }
        red[0][kk][threadIdx.x & 15] = sa;
        red[1][kk][threadIdx.x & 15] = sb;
        __syncthreads();

        if (threadIdx.x < 32) {
            int which = threadIdx.x >> 4;
            int kk2   = threadIdx.x & 15;
            float s = 0.f;
            #pragma unroll
            for (int g = 0; g < 16; ++g) s += red[which][kk2][g];
            float* dst = which == 0 ? ha : hb;
            dst[(size_t)slot * HDIM + kc * KCHUNK + kk2] = s;
        }
        __syncthreads();
    }
}

// ---------------- build valid pair list ----------------
__global__ void pairs_kernel(const int* __restrict__ candSlot,
                             int* __restrict__ pairCount, int* __restrict__ pairList)
{
    int idx = blockIdx.x * 256 + threadIdx.x;  // b*65536 + i*256 + j, 0..262143
    int b = idx >> 16;
    int i = (idx >> 8) & 255;
    int j = idx & 255;
    if (i == j) return;
    if (candSlot[b * 256 + i] >= 0 && candSlot[b * 256 + j] >= 0) {
        int p = atomicAdd(pairCount, 1);
        pairList[p] = idx;
    }
}

// ---------------- sparse pair logits ----------------
__global__ __launch_bounds__(256) void pair_kernel(
    const float* __restrict__ ha, const float* __restrict__ hb,
    const float* __restrict__ bp1, const float* __restrict__ Wp2,
    const float* __restrict__ bp2, const int* __restrict__ candSlot,
    const int* __restrict__ pairCount, const int* __restrict__ pairList,
    float* __restrict__ out)
{
    __shared__ float v[HDIM];
    const int np = *pairCount;
    for (int p = blockIdx.x; p < np; p += gridDim.x) {
        int idx = pairList[p];
        int b = idx >> 16;
        int i = (idx >> 8) & 255;
        int j = idx & 255;
        int si = candSlot[b * 256 + i];
        int sj = candSlot[b * 256 + j];
        for (int h = threadIdx.x; h < HDIM; h += 256) {
            float t = ha[(size_t)si * HDIM + h] + hb[(size_t)sj * HDIM + h] + bp1[h];
            v[h] = t > 0.f ? t : 0.f;
        }
        __syncthreads();
        if (threadIdx.x < PDIM) {
            const float* w = Wp2 + (size_t)threadIdx.x * HDIM;
            float s = 0.f;
            for (int h = 0; h < HDIM; h += 4) {
                float4 vv = *(const float4*)(v + h);
                float4 wv = *(const float4*)(w + h);
                s += vv.x * wv.x + vv.y * wv.y + vv.z * wv.z + vv.w * wv.w;
            }
            out[(size_t)idx * PDIM + threadIdx.x] = s + bp2[threadIdx.x];
        }
        __syncthreads();
    }
}

extern "C" void kernel_launch(void* const* d_in, const int* in_sizes, int n_in,
                              void* d_out, int out_size, void* d_ws, size_t ws_size,
                              hipStream_t stream) {
    const float* x   = (const float*)d_in[0];  // 4*256*768
    const float* W1s = (const float*)d_in[1];  // 768*768
    const float* b1s = (const float*)d_in[2];  // 768
    const float* W2s = (const float*)d_in[3];  // 2*768 (row 0 used)
    const float* b2s = (const float*)d_in[4];  // 2
    const float* Wp1 = (const float*)d_in[5];  // 768*1536
    const float* bp1 = (const float*)d_in[6];  // 768
    const float* Wp2 = (const float*)d_in[7];  // 54*768
    const float* bp2 = (const float*)d_in[8];  // 54

    char* ws = (char*)d_ws;
    float* span     = (float*)(ws + SPAN_OFF);
    int*   candCnt  = (int*)(ws + CANDCNT_OFF);
    int*   pairCnt  = (int*)(ws + PAIRCNT_OFF);
    int*   candIdx  = (int*)(ws + CANDIDX_OFF);
    int*   candSlot = (int*)(ws + CANDSLOT_OFF);
    int*   pairList = (int*)(ws + PAIR_OFF);
    float* ha       = (float*)(ws + HA_OFF);
    float* hb       = (float*)(ws + HB_OFF);

    float* out = (float*)d_out;

    // zero output (masked regions must be exactly 0) and span/counters
    hipMemsetAsync(out, 0, (size_t)out_size * sizeof(float), stream);
    hipMemsetAsync(ws, 0, 8192, stream);  // span + counters

    dim3 gGemm(M_ROWS / 64, HDIM / 64);
    gemm_span_kernel<<<gGemm, 256, 0, stream>>>(x, W1s, b1s, W2s, span);

    cand_kernel<<<4, 256, 0, stream>>>(span, b2s, candCnt, candIdx, candSlot);

    hab_kernel<<<1024, 256, 0, stream>>>(x, Wp1, candCnt, candIdx, ha, hb);

    pairs_kernel<<<1024, 256, 0, stream>>>(candSlot, pairCnt, pairList);

    pair_kernel<<<256, 256, 0, stream>>>(ha, hb, bp1, Wp2, bp2,
                                         candSlot, pairCnt, pairList, out);
}

// Round 3
// 139.833 us; speedup vs baseline: 2.5551x; 1.3430x over previous
//
#include <hip/hip_runtime.h>
#include <hip/hip_bf16.h>

// B=4, S=256, H=768, P=54.
// out[b,i,j,p] = valid ? relu(ha[b,i]+hb[b,j]+bp1) . Wp2[p] + bp2[p] : 0
// valid = cand[i] & cand[j] & i!=j; cand = (relu(x W1^T + b1) . W2[0] + b2[0]) > 0.5
// cand rate ~1% -> sparse pairs.
// R1: one block reading all Wp1 = per-CU BW bound -> k-split hab.
// R2: gemm 192 blocks = 1 wave/SIMD, VALUBusy 11%, 4.1M LDS conflicts ->
//     split-K=4 (768 blocks = 3/CU), LDS stride 68 (2-way max), non-atomic
//     hpart partials + fused span+cand reduce.

#define M_ROWS 1024
#define HDIM 768
#define PDIM 54
#define MAXC 256            // candidate slot cap (actual nc ~27)
#define KCHUNK 16
#define NKC (HDIM / KCHUNK) // 48
#define KSPLIT 4
#define KSEG (HDIM / KSPLIT) // 192

// ---- workspace layout (bytes) ----
#define CANDCNT_OFF  0
#define PAIRCNT_OFF  4
#define SPAN_OFF     4096        // 1024 f32 (fallback path only)
#define CANDIDX_OFF  8192        // MAXC int
#define CANDSLOT_OFF 12288       // 1024 int
#define PAIR_OFF     16384       // up to 261120 int
#define HPART_OFF    1064960     // 4*1024*768 f32 = 12 MB (big-ws path)
#define WS_NEEDED_BIG (HPART_OFF + (size_t)KSPLIT*M_ROWS*HDIM*4 + 2*(size_t)MAXC*HDIM*4)

// ================= big-ws path: split-K GEMM =================
// 64x64 tile, K-seg 192, 256 thr, 4x4 micro. Writes hpart[z][m][n].
__global__ __launch_bounds__(256) void gemm_k_kernel(
    const float* __restrict__ x, const float* __restrict__ W1,
    float* __restrict__ hpart)
{
    __shared__ float As[16][68];
    __shared__ float Bs[16][68];

    const int m0 = blockIdx.x * 64;
    const int n0 = blockIdx.y * 64;
    const int kb = blockIdx.z * KSEG;
    const int t  = threadIdx.x;
    const int tm = t & 15;
    const int tn = t >> 4;
    const int r  = t >> 2;
    const int c4 = (t & 3) * 4;

    float acc[4][4] = {};

    for (int k0 = kb; k0 < kb + KSEG; k0 += 16) {
        float4 av = *(const float4*)(x  + (size_t)(m0 + r) * HDIM + k0 + c4);
        float4 bv = *(const float4*)(W1 + (size_t)(n0 + r) * HDIM + k0 + c4);
        As[c4+0][r] = av.x; As[c4+1][r] = av.y; As[c4+2][r] = av.z; As[c4+3][r] = av.w;
        Bs[c4+0][r] = bv.x; Bs[c4+1][r] = bv.y; Bs[c4+2][r] = bv.z; Bs[c4+3][r] = bv.w;
        __syncthreads();
        #pragma unroll
        for (int kk = 0; kk < 16; ++kk) {
            float a[4], b[4];
            #pragma unroll
            for (int i = 0; i < 4; ++i) a[i] = As[kk][tm * 4 + i];
            #pragma unroll
            for (int j = 0; j < 4; ++j) b[j] = Bs[kk][tn * 4 + j];
            #pragma unroll
            for (int i = 0; i < 4; ++i)
                #pragma unroll
                for (int j = 0; j < 4; ++j)
                    acc[i][j] += a[i] * b[j];
        }
        __syncthreads();
    }

    // direct float4 stores: per instr, 16 rows x 64B full lines (coalesced)
    float* dst = hpart + (size_t)blockIdx.z * (M_ROWS * HDIM);
    #pragma unroll
    for (int i = 0; i < 4; ++i) {
        float4 v = make_float4(acc[i][0], acc[i][1], acc[i][2], acc[i][3]);
        *(float4*)(dst + (size_t)(m0 + tm * 4 + i) * HDIM + n0 + tn * 4) = v;
    }
}

// reduce 4 partials, relu.w2, decide cand. One block per row m.
__global__ __launch_bounds__(256) void span_cand_kernel(
    const float* __restrict__ hpart, const float* __restrict__ b1,
    const float* __restrict__ w2row, const float* __restrict__ b2,
    int* __restrict__ candCount, int* __restrict__ candIdx,
    int* __restrict__ candSlot)
{
    const int m = blockIdx.x;
    const int t = threadIdx.x;
    float p = 0.f;
    for (int n = t; n < HDIM; n += 256) {
        float v = hpart[(size_t)m * HDIM + n]
                + hpart[(size_t)(M_ROWS * HDIM) + (size_t)m * HDIM + n]
                + hpart[(size_t)(2 * M_ROWS * HDIM) + (size_t)m * HDIM + n]
                + hpart[(size_t)(3 * M_ROWS * HDIM) + (size_t)m * HDIM + n];
        v += b1[n];
        v = v > 0.f ? v : 0.f;
        p += v * w2row[n];
    }
    __shared__ float wred[4];
    #pragma unroll
    for (int off = 32; off > 0; off >>= 1) p += __shfl_down(p, off, 64);
    if ((t & 63) == 0) wred[t >> 6] = p;
    __syncthreads();
    if (t == 0) {
        float s = wred[0] + wred[1] + wred[2] + wred[3] + b2[0];
        if (s > 0.5f) {
            int sl = atomicAdd(candCount, 1);
            if (sl < MAXC) { candIdx[sl] = m; candSlot[m] = sl; }
            else candSlot[m] = -1;
        } else {
            candSlot[m] = -1;
        }
    }
}

// ================= fallback path (small ws): proven R2 kernels =================
__global__ __launch_bounds__(256) void gemm_span_kernel(
    const float* __restrict__ x, const float* __restrict__ W1,
    const float* __restrict__ b1, const float* __restrict__ w2row,
    float* __restrict__ span)
{
    __shared__ float As[16][68];
    __shared__ float Bs[16][68];
    __shared__ float rowpart[64][17];

    const int m0 = blockIdx.x * 64;
    const int n0 = blockIdx.y * 64;
    const int t  = threadIdx.x;
    const int tm = t & 15;
    const int tn = t >> 4;
    float acc[4][4] = {};
    const int r  = t >> 2;
    const int c4 = (t & 3) * 4;

    for (int k0 = 0; k0 < HDIM; k0 += 16) {
        float4 av = *(const float4*)(x  + (size_t)(m0 + r) * HDIM + k0 + c4);
        float4 bv = *(const float4*)(W1 + (size_t)(n0 + r) * HDIM + k0 + c4);
        As[c4+0][r] = av.x; As[c4+1][r] = av.y; As[c4+2][r] = av.z; As[c4+3][r] = av.w;
        Bs[c4+0][r] = bv.x; Bs[c4+1][r] = bv.y; Bs[c4+2][r] = bv.z; Bs[c4+3][r] = bv.w;
        __syncthreads();
        #pragma unroll
        for (int kk = 0; kk < 16; ++kk) {
            float a[4], b[4];
            #pragma unroll
            for (int i = 0; i < 4; ++i) a[i] = As[kk][tm * 4 + i];
            #pragma unroll
            for (int j = 0; j < 4; ++j) b[j] = Bs[kk][tn * 4 + j];
            #pragma unroll
            for (int i = 0; i < 4; ++i)
                #pragma unroll
                for (int j = 0; j < 4; ++j)
                    acc[i][j] += a[i] * b[j];
        }
        __syncthreads();
    }
    float part[4];
    #pragma unroll
    for (int i = 0; i < 4; ++i) {
        float s = 0.f;
        #pragma unroll
        for (int j = 0; j < 4; ++j) {
            int n = n0 + tn * 4 + j;
            float h = acc[i][j] + b1[n];
            h = h > 0.f ? h : 0.f;
            s += h * w2row[n];
        }
        part[i] = s;
    }
    #pragma unroll
    for (int i = 0; i < 4; ++i) rowpart[tm * 4 + i][tn] = part[i];
    __syncthreads();
    if (t < 64) {
        float s = 0.f;
        #pragma unroll
        for (int c = 0; c < 16; ++c) s += rowpart[t][c];
        atomicAdd(&span[m0 + t], s);
    }
}

__global__ void cand_kernel(const float* __restrict__ span, const float* __restrict__ b2,
                            int* __restrict__ candCount, int* __restrict__ candIdx,
                            int* __restrict__ candSlot)
{
    int i = blockIdx.x * 256 + threadIdx.x;
    float v = span[i] + b2[0];
    if (v > 0.5f) {
        int s = atomicAdd(candCount, 1);
        if (s < MAXC) { candIdx[s] = i; candSlot[i] = s; }
        else candSlot[i] = -1;
    } else {
        candSlot[i] = -1;
    }
}

// ================= shared downstream =================
__global__ __launch_bounds__(256) void hab_kernel(
    const float* __restrict__ x, const float* __restrict__ Wp1,
    const int* __restrict__ candCount, const int* __restrict__ candIdx,
    float* __restrict__ ha, float* __restrict__ hb)
{
    __shared__ float xs[HDIM];
    __shared__ float red[2][KCHUNK][17];
    int nc = *candCount; if (nc > MAXC) nc = MAXC;
    const int nitems = nc * NKC;
    const int kk  = threadIdx.x >> 4;
    const int hb0 = (threadIdx.x & 15) * 4;

    for (int item = blockIdx.x; item < nitems; item += gridDim.x) {
        int slot = item / NKC;
        int kc   = item % NKC;
        int row  = candIdx[slot];

        for (int h = threadIdx.x; h < HDIM; h += 256)
            xs[h] = x[(size_t)row * HDIM + h];
        __syncthreads();

        int k = kc * KCHUNK + kk;
        const float* wr = Wp1 + (size_t)k * (2 * HDIM);
        float sa = 0.f, sb = 0.f;
        #pragma unroll
        for (int h = hb0; h < HDIM; h += 64) {
            float4 xv = *(const float4*)(xs + h);
            float4 wa = *(const float4*)(wr + h);
            float4 wb = *(const float4*)(wr + HDIM + h);
            sa += xv.x * wa.x + xv.y * wa.y + xv.z * wa.z + xv.w * wa.w;
            sb += xv.x * wb.x + xv.y * wb.y + xv.z * wb.z + xv.w * wb.w;
        }
        red[0][kk][threadIdx.x & 15] = sa;
        red[1][kk][threadIdx.x & 15] = sb;
        __syncthreads();

        if (threadIdx.x < 32) {
            int which = threadIdx.x >> 4;
            int kk2   = threadIdx.x & 15;
            float s = 0.f;
            #pragma unroll
            for (int g = 0; g < 16; ++g) s += red[which][kk2][g];
            float* dst = which == 0 ? ha : hb;
            dst[(size_t)slot * HDIM + kc * KCHUNK + kk2] = s;
        }
        __syncthreads();
    }
}

__global__ void pairs_kernel(const int* __restrict__ candSlot,
                             int* __restrict__ pairCount, int* __restrict__ pairList)
{
    int idx = blockIdx.x * 256 + threadIdx.x;
    int b = idx >> 16;
    int i = (idx >> 8) & 255;
    int j = idx & 255;
    if (i == j) return;
    if (candSlot[b * 256 + i] >= 0 && candSlot[b * 256 + j] >= 0) {
        int p = atomicAdd(pairCount, 1);
        pairList[p] = idx;
    }
}

__global__ __launch_bounds__(256) void pair_kernel(
    const float* __restrict__ ha, const float* __restrict__ hb,
    const float* __restrict__ bp1, const float* __restrict__ Wp2,
    const float* __restrict__ bp2, const int* __restrict__ candSlot,
    const int* __restrict__ pairCount, const int* __restrict__ pairList,
    float* __restrict__ out)
{
    __shared__ float v[HDIM];
    __shared__ float red[4][PDIM + 2];
    const int np = *pairCount;
    const int t = threadIdx.x;
    for (int p = blockIdx.x; p < np; p += gridDim.x) {
        int idx = pairList[p];
        int b = idx >> 16;
        int i = (idx >> 8) & 255;
        int j = idx & 255;
        int si = candSlot[b * 256 + i];
        int sj = candSlot[b * 256 + j];
        if (t < 192) {
            float4 a4 = *(const float4*)(ha + (size_t)si * HDIM + t * 4);
            float4 b4 = *(const float4*)(hb + (size_t)sj * HDIM + t * 4);
            float4 c4 = *(const float4*)(bp1 + t * 4);
            float4 r;
            r.x = a4.x + b4.x + c4.x; r.x = r.x > 0.f ? r.x : 0.f;
            r.y = a4.y + b4.y + c4.y; r.y = r.y > 0.f ? r.y : 0.f;
            r.z = a4.z + b4.z + c4.z; r.z = r.z > 0.f ? r.z : 0.f;
            r.w = a4.w + b4.w + c4.w; r.w = r.w > 0.f ? r.w : 0.f;
            *(float4*)(v + t * 4) = r;
        }
        __syncthreads();
        if (t < 216) {
            int pp  = t % PDIM;
            int seg = t / PDIM;               // 0..3, h-range 192 each
            const float* w = Wp2 + (size_t)pp * HDIM + seg * 192;
            const float* vv = v + seg * 192;
            float s = 0.f;
            for (int h = 0; h < 192; h += 4) {
                float4 a = *(const float4*)(vv + h);
                float4 b2_ = *(const float4*)(w + h);
                s += a.x * b2_.x + a.y * b2_.y + a.z * b2_.z + a.w * b2_.w;
            }
            red[seg][pp] = s;
        }
        __syncthreads();
        if (t < PDIM)
            out[(size_t)idx * PDIM + t] = red[0][t] + red[1][t] + red[2][t] + red[3][t] + bp2[t];
        __syncthreads();
    }
}

extern "C" void kernel_launch(void* const* d_in, const int* in_sizes, int n_in,
                              void* d_out, int out_size, void* d_ws, size_t ws_size,
                              hipStream_t stream) {
    const float* x   = (const float*)d_in[0];
    const float* W1s = (const float*)d_in[1];
    const float* b1s = (const float*)d_in[2];
    const float* W2s = (const float*)d_in[3];
    const float* b2s = (const float*)d_in[4];
    const float* Wp1 = (const float*)d_in[5];
    const float* bp1 = (const float*)d_in[6];
    const float* Wp2 = (const float*)d_in[7];
    const float* bp2 = (const float*)d_in[8];

    char* ws = (char*)d_ws;
    int*   candCnt  = (int*)(ws + CANDCNT_OFF);
    int*   pairCnt  = (int*)(ws + PAIRCNT_OFF);
    float* span     = (float*)(ws + SPAN_OFF);
    int*   candIdx  = (int*)(ws + CANDIDX_OFF);
    int*   candSlot = (int*)(ws + CANDSLOT_OFF);
    int*   pairList = (int*)(ws + PAIR_OFF);
    float* out = (float*)d_out;

    const bool bigws = ws_size >= WS_NEEDED_BIG;
    float* hpart; float* ha; float* hb;
    if (bigws) {
        hpart = (float*)(ws + HPART_OFF);
        ha = hpart + (size_t)KSPLIT * M_ROWS * HDIM;
        hb = ha + (size_t)MAXC * HDIM;
    } else {
        hpart = nullptr;
        ha = (float*)(ws + HPART_OFF);          // 256*768 f32
        hb = ha + (size_t)MAXC * HDIM;
    }

    hipMemsetAsync(out, 0, (size_t)out_size * sizeof(float), stream);
    hipMemsetAsync(ws, 0, 8192, stream);  // counters + span

    if (bigws) {
        dim3 g(M_ROWS / 64, HDIM / 64, KSPLIT);
        gemm_k_kernel<<<g, 256, 0, stream>>>(x, W1s, hpart);
        span_cand_kernel<<<M_ROWS, 256, 0, stream>>>(hpart, b1s, W2s, b2s,
                                                     candCnt, candIdx, candSlot);
    } else {
        dim3 g(M_ROWS / 64, HDIM / 64);
        gemm_span_kernel<<<g, 256, 0, stream>>>(x, W1s, b1s, W2s, span);
        cand_kernel<<<4, 256, 0, stream>>>(span, b2s, candCnt, candIdx, candSlot);
    }

    hab_kernel<<<2048, 256, 0, stream>>>(x, Wp1, candCnt, candIdx, ha, hb);
    pairs_kernel<<<1024, 256, 0, stream>>>(candSlot, pairCnt, pairList);
    pair_kernel<<<512, 256, 0, stream>>>(ha, hb, bp1, Wp2, bp2,
                                         candSlot, pairCnt, pairList, out);
}